// Round 11
// baseline (284.936 us; speedup 1.0000x reference)
//
#include <hip/hip_runtime.h>
#include <math.h>

#define CIN 512
#define NCLS 10
#define KDIM 4608            // 512*9
#define NTOT 6400            // 256*25
#define MPAD 640
#define BK 128
#define NKT 36               // KDIM/BK
#define NABLK (5 * NKT)      // 180 A-tile blocks in pack_a
#define LN2PI_F 1.8378770664093453f

typedef __attribute__((ext_vector_type(8))) short bf16x8;
typedef __attribute__((ext_vector_type(4))) float f32x4;

typedef const __attribute__((address_space(1))) void* gas_ptr;
typedef __attribute__((address_space(3))) void* las_ptr;

__device__ __forceinline__ void async_copy16(const void* g, void* l) {
    __builtin_amdgcn_global_load_lds((gas_ptr)g, (las_ptr)l, 16, 0, 0);
}

__device__ __forceinline__ unsigned short f2bf(float f) {
    unsigned int u = __float_as_uint(f);
    u = (u + 0x7fffu + ((u >> 16) & 1u)) >> 16;   // RNE
    return (unsigned short)u;
}
__device__ __forceinline__ float bf2f(unsigned short s) {
    return __uint_as_float(((unsigned int)s) << 16);
}
__device__ __forceinline__ float fexp(float x) { return __expf(x); }
__device__ __forceinline__ float flog(float x) { return __logf(x); }

// ---------------------------------------------------------------------------
// pack_a: blocks [0,180): weights fp32 -> bf16 pre-tiled for the GEMM's LDS
// staging order. Blocks [180, 243): Wm fp32 -> bf16 em re-layout.
// Block 0: folded BN scale/bias + ZEROES the em rendezvous flags (stream
// order guarantees this completes before em_kernel launches).
// Wmb stays bf16 (R20: f32 W thrashed L2 — FETCH 13->337 MB).
// ---------------------------------------------------------------------------
__global__ __launch_bounds__(256) void pack_a_kernel(
    const float* __restrict__ w_pose, const float* __restrict__ w_a,
    const float* __restrict__ bn_p_g, const float* __restrict__ bn_p_b,
    const float* __restrict__ bn_p_m, const float* __restrict__ bn_p_v,
    const float* __restrict__ bn_a_g, const float* __restrict__ bn_a_b,
    const float* __restrict__ bn_a_m, const float* __restrict__ bn_a_v,
    const float* __restrict__ Wm,
    unsigned short* __restrict__ At, unsigned short* __restrict__ Wmb,
    float* __restrict__ sc, float* __restrict__ bi,
    int* __restrict__ flags)
{
    const int blk = blockIdx.x;
    const int t = threadIdx.x;

    if (blk >= NABLK) {                          // ---- Wm bf16 packing ----
        const int chunk = (blk - NABLK) * 256 + t;   // 8 floats per chunk
        if (chunk < 16000) {
            const int e = chunk >> 1, half = chunk & 1;   // entry = (m,c), 16 floats
            const int m = e / 10, c = e - m * 10;
            const int kk = m >> 5, a = m & 31;
            const int de = (kk * 10 + c) * 32 + a;        // transposed entry
            const float4* s4 = reinterpret_cast<const float4*>(Wm + (size_t)chunk * 8);
            float4 x0 = s4[0], x1 = s4[1];
            int4 o;
            o.x = (int)f2bf(x0.x) | ((int)f2bf(x0.y) << 16);
            o.y = (int)f2bf(x0.z) | ((int)f2bf(x0.w) << 16);
            o.z = (int)f2bf(x1.x) | ((int)f2bf(x1.y) << 16);
            o.w = (int)f2bf(x1.z) | ((int)f2bf(x1.w) << 16);
            reinterpret_cast<int4*>(Wmb + ((size_t)de * 2 + half) * 8)[0] = o;
        }
        return;
    }

    const int mblk = blk / NKT;
    if (blk == 0) {
        for (int i = t; i < MPAD; i += 256) {
            float s = 0.f, b = 0.f;
            if (i < 512) {
                s = bn_p_g[i] / sqrtf(bn_p_v[i] + 1e-5f);
                b = bn_p_b[i] - bn_p_m[i] * s;
            } else if (i < 544) {
                const int j = i - 512;
                s = bn_a_g[j] / sqrtf(bn_a_v[j] + 1e-5f);
                b = bn_a_b[j] - bn_a_m[j] * s;
            }
            sc[i] = s; bi[i] = b;
        }
        for (int i = t; i < 512; i += 256) flags[i] = 0;   // em rendezvous flags
    }

    const int kt = blk - mblk * NKT;
    #pragma unroll
    for (int j = 0; j < 8; ++j) {
        const int c = t + j * 256;               // 0..2047
        const int kc8 = c >> 7, slot = c & 127;
        const int row = mblk * 128 + (slot ^ (kc8 << 2));
        const int k0 = (kt * 16 + kc8) * 8;
        float v[8] = {0.f,0.f,0.f,0.f,0.f,0.f,0.f,0.f};
        if (row < 512) {
            const float4* s4 = reinterpret_cast<const float4*>(w_pose + (size_t)row * KDIM + k0);
            float4 x0 = s4[0], x1 = s4[1];
            v[0]=x0.x; v[1]=x0.y; v[2]=x0.z; v[3]=x0.w;
            v[4]=x1.x; v[5]=x1.y; v[6]=x1.z; v[7]=x1.w;
        } else if (row < 544) {
            const float4* s4 = reinterpret_cast<const float4*>(w_a + (size_t)(row - 512) * KDIM + k0);
            float4 x0 = s4[0], x1 = s4[1];
            v[0]=x0.x; v[1]=x0.y; v[2]=x0.z; v[3]=x0.w;
            v[4]=x1.x; v[5]=x1.y; v[6]=x1.z; v[7]=x1.w;
        }
        int4 o;
        o.x = (int)f2bf(v[0]) | ((int)f2bf(v[1]) << 16);
        o.y = (int)f2bf(v[2]) | ((int)f2bf(v[3]) << 16);
        o.z = (int)f2bf(v[4]) | ((int)f2bf(v[5]) << 16);
        o.w = (int)f2bf(v[6]) | ((int)f2bf(v[7]) << 16);
        reinterpret_cast<int4*>(At + ((((size_t)blk) << 11) + c) * 8)[0] = o;
    }
}

// ---------------------------------------------------------------------------
// pack_b: im2col fp32->bf16, pre-tiled, px-major work order (R10 win).
// ---------------------------------------------------------------------------
__global__ __launch_bounds__(1024) void pack_b_kernel(
    const float* __restrict__ x, unsigned short* __restrict__ Bt)
{
    __shared__ __align__(16) float xs[CIN * 25];
    const int b = blockIdx.x;
    const int t = threadIdx.x;
    const float4* xb = reinterpret_cast<const float4*>(x + (size_t)b * (CIN * 25));
    for (int f4 = t; f4 < (CIN * 25) / 4; f4 += 1024)
        reinterpret_cast<float4*>(xs)[f4] = xb[f4];
    __syncthreads();

    for (int w = t; w < 25 * (KDIM / 8); w += 1024) {
        const int ch = w / 25;                   // k-chunk (px-major order)
        const int px = w - ch * 25;
        const int py = px / 5, qx = px % 5;
        const int k0 = ch * 8;
        unsigned short v[8];
        #pragma unroll
        for (int j = 0; j < 8; ++j) {
            const int k = k0 + j;
            const int ci = k / 9;
            const int kk = k - ci * 9;
            const int dy = kk / 3, dx = kk - dy * 3;
            const int yy = py + dy - 1, xx = qx + dx - 1;
            const bool ok = (yy >= 0) & (yy < 5) & (xx >= 0) & (xx < 5);
            v[j] = ok ? f2bf(xs[ci * 25 + yy * 5 + xx]) : (unsigned short)0;
        }
        int4 o;
        o.x = (int)v[0] | ((int)v[1] << 16);
        o.y = (int)v[2] | ((int)v[3] << 16);
        o.z = (int)v[4] | ((int)v[5] << 16);
        o.w = (int)v[6] | ((int)v[7] << 16);
        const int n = b * 25 + px;
        const int nblk = n >> 7, nr = n & 127;
        const int kt = k0 >> 7;
        const int kc8 = (k0 >> 3) & 15;
        const int c = kc8 * 128 + (nr ^ (kc8 << 2));
        reinterpret_cast<int4*>(Bt + ((((size_t)(nblk * NKT + kt)) << 11) + c) * 8)[0] = o;
    }
}

// ---------------------------------------------------------------------------
// gemm: R11 shape (1024 threads = 4 K-groups x (2x2) waves, 64x64 wave tile,
// BK=128 double-buffered, XCD-swizzled grid, bf16 Cp / fp32 Ca split).
// ---------------------------------------------------------------------------
__global__ __launch_bounds__(1024) void gemm_kernel(
    const unsigned short* __restrict__ At,
    const unsigned short* __restrict__ Bt,
    const float* __restrict__ sc, const float* __restrict__ bi,
    unsigned short* __restrict__ Cp,        // [512][6400] bf16
    float* __restrict__ Ca)                 // [32][6400] fp32
{
    __shared__ __align__(16) unsigned char smem[131072];
    const int t = threadIdx.x;
    const int L = blockIdx.x;
    int mblk, nblk;
    if (L >= 240) { const int i = L - 240; mblk = i >> 1; nblk = 48 + (i & 1); }
    else          { const int q = L / 40, r = L - q * 40;
                    mblk = r >> 3; nblk = q * 8 + (r & 7); }
    const int m0 = mblk * 128, n0 = nblk * 128;
    const int lane = t & 63, w = t >> 6;
    const int g = w >> 2, wq = w & 3;          // 4 K-groups x 4 tile-waves
    const int wm = wq >> 1, wn = wq & 1;
    const int row16 = lane & 15, quad = lane >> 4;

    f32x4 acc[4][4] = {};

    const unsigned short* gAbase = At + (((size_t)mblk * NKT) << 14);
    const unsigned short* gBbase = Bt + (((size_t)nblk * NKT) << 14);

    #define STAGE(kt, s)                                                      \
    {                                                                         \
        unsigned short* As_ = (unsigned short*)(smem + (s) * 65536);          \
        unsigned short* Bs_ = As_ + 16384;                                    \
        const unsigned short* ga = gAbase + ((size_t)(kt) << 14);             \
        const unsigned short* gb = gBbase + ((size_t)(kt) << 14);             \
        _Pragma("unroll")                                                     \
        for (int j = 0; j < 2; ++j) {                                         \
            async_copy16(ga + ((size_t)(j * 1024 + t) << 3),                  \
                         As_ + ((size_t)(j * 1024 + w * 64) << 3));           \
            async_copy16(gb + ((size_t)(j * 1024 + t) << 3),                  \
                         Bs_ + ((size_t)(j * 1024 + w * 64) << 3));           \
        }                                                                     \
    }

    #define COMPUTE(s)                                                        \
    {                                                                         \
        const unsigned short* As_ = (const unsigned short*)(smem + (s) * 65536);\
        const unsigned short* Bs_ = As_ + 16384;                              \
        const int kc8b = g * 4 + quad;                                        \
        const int sw = kc8b << 2;                                             \
        bf16x8 af[4], bfr[4];                                                 \
        _Pragma("unroll")                                                     \
        for (int mt = 0; mt < 4; ++mt)                                        \
            af[mt] = *reinterpret_cast<const bf16x8*>(                        \
                &As_[(size_t)(kc8b * 128 + ((wm * 64 + mt * 16 + row16) ^ sw)) * 8]);\
        _Pragma("unroll")                                                     \
        for (int nt = 0; nt < 4; ++nt)                                        \
            bfr[nt] = *reinterpret_cast<const bf16x8*>(                       \
                &Bs_[(size_t)(kc8b * 128 + ((wn * 64 + nt * 16 + row16) ^ sw)) * 8]);\
        _Pragma("unroll")                                                     \
        for (int mt = 0; mt < 4; ++mt)                                        \
            _Pragma("unroll")                                                 \
            for (int nt = 0; nt < 4; ++nt)                                    \
                acc[mt][nt] = __builtin_amdgcn_mfma_f32_16x16x32_bf16(        \
                    af[mt], bfr[nt], acc[mt][nt], 0, 0, 0);                   \
    }

    STAGE(0, 0);
    for (int kt = 0; kt < NKT; ++kt) {
        __syncthreads();
        if (kt + 1 < NKT) STAGE(kt + 1, (kt + 1) & 1);
        COMPUTE(kt & 1);
    }
    #undef STAGE
    #undef COMPUTE

    // merge the 4 K-groups into group 0 (3 rounds through 64 KB of LDS)
    f32x4* mb = (f32x4*)smem;                 // 4096 f32x4 slots
    #pragma unroll
    for (int r = 1; r < 4; ++r) {
        __syncthreads();
        if (g == r) {
            f32x4* dst = mb + wq * 1024;
            #pragma unroll
            for (int i = 0; i < 16; ++i)
                dst[i * 64 + lane] = acc[i >> 2][i & 3];
        }
        __syncthreads();
        if (g == 0) {
            const f32x4* src = mb + wq * 1024;
            #pragma unroll
            for (int i = 0; i < 16; ++i)
                acc[i >> 2][i & 3] += src[i * 64 + lane];
        }
    }

    if (g == 0) {
        #pragma unroll
        for (int mt = 0; mt < 4; ++mt) {
            const int mbase = m0 + wm * 64 + mt * 16 + quad * 4;
            if (mbase >= 544) continue;
            #pragma unroll
            for (int rg = 0; rg < 4; ++rg) {
                const int m = mbase + rg;
                const float s = sc[m], bbx = bi[m];
                #pragma unroll
                for (int nt = 0; nt < 4; ++nt) {
                    const int n = n0 + wn * 64 + nt * 16 + row16;
                    const float v = fmaf(acc[mt][nt][rg], s, bbx);
                    if (m < 512) Cp[(size_t)m * NTOT + n] = f2bf(v);
                    else Ca[(size_t)(m - 512) * NTOT + n] = 1.f / (1.f + fexp(-v));
                }
            }
        }
    }
}

// ---------------------------------------------------------------------------
// EM routing — R22: kk-SPLIT PAIR per batch. 512 blocks (2 per batch, kk
// 0..12 / 13..24) -> 2 blocks/CU = 20 waves (R21 was latency-bound at 10).
// Insight: phase R's class softmax at position m is kk-LOCAL; the only
// cross-half coupling is the 33-float/class S reduction + epilogue. Pairs
// rendezvous 3x (once per EM iteration) via per-iteration global partial
// slots + release/acquire flags (device-scope atomics, s_sleep spin).
// Epilogue recomputed redundantly by both halves (no second sync).
// Residency guaranteed by capacity: LDS ~33 KB -> 3+ blocks/CU >= 2 needed.
// Flags zeroed by pack_a (stream-ordered). Loop bodies identical to R21
// (same ~72 VGPR profile — no allocator trap). Only the S-sum association
// changes (local+partner, like R12's 3-way merge: same absmax).
// ---------------------------------------------------------------------------
__global__ __launch_bounds__(640, 1) void em_kernel(
    const unsigned short* __restrict__ Cp,    // [512][6400] bf16 pose
    const float* __restrict__ Ca,             // [32][6400] fp32 activations
    const unsigned short* __restrict__ Wmb,   // [25][10][32][16] bf16
    const float* __restrict__ beta_u, const float* __restrict__ beta_a,
    float* __restrict__ part,                 // [256][2][3][10][33] f32
    int* __restrict__ flags,                  // [256][2]
    float* __restrict__ out)                  // (256,10)
{
    __shared__ __align__(16) unsigned short psh[13][2][32][8]; // 13.3 KB bf16 pose
    __shared__ float aush[416];
    __shared__ float lnq[NCLS][416];                           // 16.6 KB, reused as rw
    __shared__ float mu_sh[NCLS][16];
    __shared__ float i2s_sh[NCLS][16];
    __shared__ float costp[2][NCLS];
    __shared__ float slgp[2][NCLS];
    __shared__ float Kc_sh[NCLS];
    __shared__ float aout_sh[NCLS];

    const int bid = blockIdx.x;
    const int b = bid >> 1, half = bid & 1;
    const int t = threadIdx.x;
    const int c = t >> 6;                     // wave = class
    const int rh = (t >> 5) & 1;              // half-wave = pose-dim half
    const int a = t & 31;                     // capsule lane
    const int klo = half ? 13 : 0;
    const int knum = half ? 12 : 13;
    const int NM = knum << 5;                 // local positions (416 / 384)

    int* myFlag  = flags + b * 2 + half;
    int* othFlag = flags + b * 2 + (half ^ 1);

    // stage local pose: Cp[c2][b*25+klo+pxl] -> psh[pxl][(c2&15)>>3][c2>>4][c2&7]
    const unsigned short* pb = Cp + (size_t)b * 25 + klo;
    for (int f = t; f < (knum << 9); f += 640) {
        const int c2 = f / knum, pxl = f - c2 * knum;
        const int e = c2 & 15;
        psh[pxl][e >> 3][c2 >> 4][e & 7] = pb[(size_t)c2 * NTOT + pxl];
    }
    const float* ab = Ca + (size_t)b * 25 + klo;
    for (int f = t; f < NM; f += 640) {
        const int pxl = f >> 5, ci = f & 31;
        aush[pxl * 32 + ci] = ab[(size_t)ci * NTOT + pxl];
    }
    __syncthreads();

    const float bu = beta_u[c], ba = beta_a[c];
    float muL[8], i2sL[8], KcL = 0.f;
    const unsigned short* wlo = Wmb + ((size_t)(c * 32 + a)) * 16
                                    + (size_t)klo * 5120;   // + kk*5120 (local)

    // unpack 16 bf16 W (w0_,w1_) + 8 bf16 pose (p_), 32 FMA vote
    #define VOTE(w0_, w1_, p_, vv)                                           \
        {                                                                    \
            float pm[8], wv[16];                                             \
            const unsigned int pu[4] = {(unsigned)p_.x, (unsigned)p_.y,      \
                                        (unsigned)p_.z, (unsigned)p_.w};     \
            _Pragma("unroll")                                                \
            for (int i = 0; i < 4; ++i) {                                    \
                pm[2*i]   = __uint_as_float(pu[i] << 16);                    \
                pm[2*i+1] = __uint_as_float(pu[i] & 0xFFFF0000u);            \
            }                                                                \
            const unsigned int uu[8] = {(unsigned)w0_.x,(unsigned)w0_.y,     \
                (unsigned)w0_.z,(unsigned)w0_.w,(unsigned)w1_.x,             \
                (unsigned)w1_.y,(unsigned)w1_.z,(unsigned)w1_.w};            \
            _Pragma("unroll")                                                \
            for (int i = 0; i < 8; ++i) {                                    \
                wv[2*i]   = __uint_as_float(uu[i] << 16);                    \
                wv[2*i+1] = __uint_as_float(uu[i] & 0xFFFF0000u);            \
            }                                                                \
            _Pragma("unroll")                                                \
            for (int jr = 0; jr < 2; ++jr) {                                 \
                _Pragma("unroll")                                            \
                for (int s = 0; s < 4; ++s) {                                \
                    float av = 0.f;                                          \
                    _Pragma("unroll")                                        \
                    for (int tt = 0; tt < 4; ++tt)                           \
                        av = fmaf(pm[jr*4+tt], wv[tt*4+s], av);              \
                    vv[jr*4+s] = av;                                         \
                }                                                            \
            }                                                                \
        }

    float p95 = 1.f;
    for (int it = 0; it < 3; ++it) {
        p95 *= 0.95f;
        const float lam = 0.01f * (1.f - p95);

        if (it > 0) {
            // ---- phase A: ln_p over local kks, W+pose depth-1 prefetch ----
            int4 wr0 = *reinterpret_cast<const int4*>(wlo);
            int4 wr1 = *reinterpret_cast<const int4*>(wlo + 8);
            int4 pr  = *reinterpret_cast<const int4*>(&psh[0][rh][a][0]);
            for (int kk = 0; kk < knum; ++kk) {
                const int4 w0 = wr0, w1 = wr1, p = pr;
                if (kk + 1 < knum) {
                    const unsigned short* wn = wlo + (size_t)(kk + 1) * 5120;
                    wr0 = *reinterpret_cast<const int4*>(wn);
                    wr1 = *reinterpret_cast<const int4*>(wn + 8);
                    pr  = *reinterpret_cast<const int4*>(&psh[kk + 1][rh][a][0]);
                }
                float vv[8];
                VOTE(w0, w1, p, vv);
                float q = (rh == 0) ? KcL : 0.f;
                #pragma unroll
                for (int j = 0; j < 8; ++j) {
                    const float d = vv[j] - muL[j];
                    q -= d * d * i2sL[j];
                }
                q += __shfl_xor(q, 32);
                if (rh == 0) lnq[c][kk * 32 + a] = q;
            }
            __syncthreads();
            // ---- phase R (local, dedup, in-place): one thread per m ----
            if (t < NM) {
                const int m = t;
                float qv[NCLS];
                #pragma unroll
                for (int cc = 0; cc < NCLS; ++cc) qv[cc] = lnq[cc][m];
                float mx = qv[0];
                #pragma unroll
                for (int cc = 1; cc < NCLS; ++cc) mx = fmaxf(mx, qv[cc]);
                float ev[NCLS];
                float den = 0.f;
                #pragma unroll
                for (int cc = 0; cc < NCLS; ++cc) {
                    ev[cc] = fexp(qv[cc] - mx);
                    den += ev[cc];
                }
                const float s = aush[m] * __builtin_amdgcn_rcpf(den);
                #pragma unroll
                for (int cc = 0; cc < NCLS; ++cc)
                    lnq[cc][m] = ev[cc] * s;
            }
            __syncthreads();
        }

        // ---- phase S: weighted stats over local kks, W depth-2 prefetch ----
        float S0 = 0.f, S1[8], S2[8];
        #pragma unroll
        for (int j = 0; j < 8; ++j) { S1[j] = 0.f; S2[j] = 0.f; }

        int4 wA0 = *reinterpret_cast<const int4*>(wlo);
        int4 wA1 = *reinterpret_cast<const int4*>(wlo + 8);
        int4 wB0 = *reinterpret_cast<const int4*>(wlo + 5120);
        int4 wB1 = *reinterpret_cast<const int4*>(wlo + 5120 + 8);
        int4 pr  = *reinterpret_cast<const int4*>(&psh[0][rh][a][0]);
        for (int kk = 0; kk < knum; ++kk) {
            const int4 w0 = wA0, w1 = wA1, p = pr;
            wA0 = wB0; wA1 = wB1;
            if (kk + 2 < knum) {
                const unsigned short* wn = wlo + (size_t)(kk + 2) * 5120;
                wB0 = *reinterpret_cast<const int4*>(wn);
                wB1 = *reinterpret_cast<const int4*>(wn + 8);
            }
            if (kk + 1 < knum)
                pr = *reinterpret_cast<const int4*>(&psh[kk + 1][rh][a][0]);
            float vv[8];
            VOTE(w0, w1, p, vv);
            const int m = kk * 32 + a;
            const float rw = (it == 0) ? aush[m] : lnq[c][m];
            S0 += rw;
            #pragma unroll
            for (int j = 0; j < 8; ++j) {
                const float rv = rw * vv[j];
                S1[j] += rv;
                S2[j] = fmaf(rv, vv[j], S2[j]);
            }
        }

        // butterfly over the 32 a-lanes (local sums)
        #pragma unroll
        for (int off = 16; off >= 1; off >>= 1) {
            S0 += __shfl_xor(S0, off);
            #pragma unroll
            for (int j = 0; j < 8; ++j) {
                S1[j] += __shfl_xor(S1[j], off);
                S2[j] += __shfl_xor(S2[j], off);
            }
        }

        // ---- publish partials (per-iteration slot), rendezvous, merge ----
        float* myPart = part + ((size_t)((b * 2 + half) * 3 + it)) * (NCLS * 33);
        const float* othPart =
            part + ((size_t)((b * 2 + (half ^ 1)) * 3 + it)) * (NCLS * 33);
        if (a == 0) {
            const int base = c * 33;
            if (rh == 0) {
                __hip_atomic_store(&myPart[base], S0,
                                   __ATOMIC_RELAXED, __HIP_MEMORY_SCOPE_AGENT);
                #pragma unroll
                for (int j = 0; j < 8; ++j) {
                    __hip_atomic_store(&myPart[base + 1 + j], S1[j],
                                       __ATOMIC_RELAXED, __HIP_MEMORY_SCOPE_AGENT);
                    __hip_atomic_store(&myPart[base + 9 + j], S2[j],
                                       __ATOMIC_RELAXED, __HIP_MEMORY_SCOPE_AGENT);
                }
            } else {
                #pragma unroll
                for (int j = 0; j < 8; ++j) {
                    __hip_atomic_store(&myPart[base + 17 + j], S1[j],
                                       __ATOMIC_RELAXED, __HIP_MEMORY_SCOPE_AGENT);
                    __hip_atomic_store(&myPart[base + 25 + j], S2[j],
                                       __ATOMIC_RELAXED, __HIP_MEMORY_SCOPE_AGENT);
                }
            }
        }
        __syncthreads();
        if (t == 0) {
            __hip_atomic_store(myFlag, it + 1,
                               __ATOMIC_RELEASE, __HIP_MEMORY_SCOPE_AGENT);
            while (__hip_atomic_load(othFlag, __ATOMIC_ACQUIRE,
                                     __HIP_MEMORY_SCOPE_AGENT) < it + 1)
                __builtin_amdgcn_s_sleep(2);
        }
        __syncthreads();
        if (a == 0) {
            const int base = c * 33;
            S0 += __hip_atomic_load(&othPart[base],
                                    __ATOMIC_RELAXED, __HIP_MEMORY_SCOPE_AGENT);
            const int o1 = rh ? 17 : 1, o2 = rh ? 25 : 9;
            #pragma unroll
            for (int j = 0; j < 8; ++j) {
                S1[j] += __hip_atomic_load(&othPart[base + o1 + j],
                                           __ATOMIC_RELAXED, __HIP_MEMORY_SCOPE_AGENT);
                S2[j] += __hip_atomic_load(&othPart[base + o2 + j],
                                           __ATOMIC_RELAXED, __HIP_MEMORY_SCOPE_AGENT);
            }
        }

        // per-half epilogue on merged sums (redundant in both pair blocks)
        if (a == 0) {
            const float s0e = S0 + 1e-12f;
            const float inv = 1.f / s0e;
            float cost_ = 0.f, slg_ = 0.f;
            #pragma unroll
            for (int j = 0; j < 8; ++j) {
                const float mu_ = S1[j] * inv;
                const float sg = (S2[j] - 2.f * mu_ * S1[j] + mu_ * mu_ * S0) * inv
                                 + 1e-12f;
                cost_ += bu + 0.5f * flog(sg);
                slg_ += flog(sg * LN2PI_F);
                mu_sh[c][rh * 8 + j] = mu_;
                i2s_sh[c][rh * 8 + j] = 0.5f / sg;
            }
            costp[rh][c] = cost_;
            slgp[rh][c] = slg_;
        }
        __syncthreads();
        if (a == 0 && rh == 0) {
            const float costsum = (costp[0][c] + costp[1][c]) * S0;
            const float aout = 1.f / (1.f + fexp(-(lam * (ba - costsum))));
            aout_sh[c] = aout;
            Kc_sh[c] = flog(aout) - 0.5f * (slgp[0][c] + slgp[1][c]);
        }
        __syncthreads();
        if (it < 2) {
            #pragma unroll
            for (int j = 0; j < 8; ++j) {
                muL[j] = mu_sh[c][rh * 8 + j];
                i2sL[j] = i2s_sh[c][rh * 8 + j];
            }
            KcL = Kc_sh[c];
        }
    }

    if (half == 0 && t < NCLS) {
        float s = 0.f;
        #pragma unroll
        for (int cc = 0; cc < NCLS; ++cc) s += aout_sh[cc];
        out[b * NCLS + t] = flog(aout_sh[t] / s);
    }
    #undef VOTE
}

// ---------------------------------------------------------------------------
extern "C" void kernel_launch(void* const* d_in, const int* in_sizes, int n_in,
                              void* d_out, int out_size, void* d_ws, size_t ws_size,
                              hipStream_t stream) {
    const float* x      = (const float*)d_in[0];
    const float* w_a    = (const float*)d_in[1];
    const float* w_pose = (const float*)d_in[2];
    const float* bn_a_g = (const float*)d_in[3];
    const float* bn_a_b = (const float*)d_in[4];
    const float* bn_a_m = (const float*)d_in[5];
    const float* bn_a_v = (const float*)d_in[6];
    const float* bn_p_g = (const float*)d_in[7];
    const float* bn_p_b = (const float*)d_in[8];
    const float* bn_p_m = (const float*)d_in[9];
    const float* bn_p_v = (const float*)d_in[10];
    const float* Wm     = (const float*)d_in[11];
    const float* beta_u = (const float*)d_in[12];
    const float* beta_a = (const float*)d_in[13];
    float* out = (float*)d_out;

    char* p = (char*)d_ws;
    unsigned short* At  = (unsigned short*)p;  p += (size_t)MPAD * KDIM * 2;
    unsigned short* Bt  = (unsigned short*)p;  p += (size_t)NTOT * KDIM * 2;
    unsigned short* Wmb = (unsigned short*)p;  p += (size_t)800 * NCLS * 16 * 2;
    unsigned short* Cp  = (unsigned short*)p;  p += (size_t)512 * NTOT * 2;
    float* Ca = (float*)p;                     p += (size_t)32 * NTOT * 4;
    float* sc = (float*)p;                     p += MPAD * 4;
    float* bi = (float*)p;                     p += MPAD * 4;
    float* part = (float*)p;                   p += (size_t)256 * 2 * 3 * NCLS * 33 * 4;
    int* flags = (int*)p;                      p += (size_t)512 * 4;

    pack_a_kernel<<<NABLK + 63, 256, 0, stream>>>(w_pose, w_a,
                                                  bn_p_g, bn_p_b, bn_p_m, bn_p_v,
                                                  bn_a_g, bn_a_b, bn_a_m, bn_a_v,
                                                  Wm, At, Wmb, sc, bi, flags);
    pack_b_kernel<<<256, 1024, 0, stream>>>(x, Bt);
    gemm_kernel<<<250, 1024, 0, stream>>>(At, Bt, sc, bi, Cp, Ca);
    em_kernel<<<512, 640, 0, stream>>>(Cp, Ca, Wmb, beta_u, beta_a,
                                       part, flags, out);
}

// Round 12
// 227.166 us; speedup vs baseline: 1.2543x; 1.2543x over previous
//
#include <hip/hip_runtime.h>
#include <math.h>

#define CIN 512
#define NCLS 10
#define KDIM 4608            // 512*9
#define NTOT 6400            // 256*25
#define MPAD 640
#define BK 128
#define NKT 36               // KDIM/BK
#define NABLK (5 * NKT)      // 180 A-tile blocks in pack_a
#define LN2PI_F 1.8378770664093453f

typedef __attribute__((ext_vector_type(8))) short bf16x8;
typedef __attribute__((ext_vector_type(4))) float f32x4;
typedef __attribute__((ext_vector_type(2))) float f32x2;

typedef const __attribute__((address_space(1))) void* gas_ptr;
typedef __attribute__((address_space(3))) void* las_ptr;

__device__ __forceinline__ void async_copy16(const void* g, void* l) {
    __builtin_amdgcn_global_load_lds((gas_ptr)g, (las_ptr)l, 16, 0, 0);
}

__device__ __forceinline__ unsigned short f2bf(float f) {
    unsigned int u = __float_as_uint(f);
    u = (u + 0x7fffu + ((u >> 16) & 1u)) >> 16;   // RNE
    return (unsigned short)u;
}
__device__ __forceinline__ float bf2f(unsigned short s) {
    return __uint_as_float(((unsigned int)s) << 16);
}
__device__ __forceinline__ float fexp(float x) { return __expf(x); }
__device__ __forceinline__ float flog(float x) { return __logf(x); }

// ---------------------------------------------------------------------------
// pack_a: blocks [0,180): weights fp32 -> bf16 pre-tiled for the GEMM's LDS
// staging order. Blocks [180, 243): Wm fp32 -> bf16 em re-layout.
// Block 0: folded BN scale/bias.
// Wmb stays bf16 (R20: f32 W thrashed L2 — FETCH 13->337 MB).
// ---------------------------------------------------------------------------
__global__ __launch_bounds__(256) void pack_a_kernel(
    const float* __restrict__ w_pose, const float* __restrict__ w_a,
    const float* __restrict__ bn_p_g, const float* __restrict__ bn_p_b,
    const float* __restrict__ bn_p_m, const float* __restrict__ bn_p_v,
    const float* __restrict__ bn_a_g, const float* __restrict__ bn_a_b,
    const float* __restrict__ bn_a_m, const float* __restrict__ bn_a_v,
    const float* __restrict__ Wm,
    unsigned short* __restrict__ At, unsigned short* __restrict__ Wmb,
    float* __restrict__ sc, float* __restrict__ bi)
{
    const int blk = blockIdx.x;
    const int t = threadIdx.x;

    if (blk >= NABLK) {                          // ---- Wm bf16 packing ----
        const int chunk = (blk - NABLK) * 256 + t;   // 8 floats per chunk
        if (chunk < 16000) {
            const int e = chunk >> 1, half = chunk & 1;   // entry = (m,c), 16 floats
            const int m = e / 10, c = e - m * 10;
            const int kk = m >> 5, a = m & 31;
            const int de = (kk * 10 + c) * 32 + a;        // transposed entry
            const float4* s4 = reinterpret_cast<const float4*>(Wm + (size_t)chunk * 8);
            float4 x0 = s4[0], x1 = s4[1];
            int4 o;
            o.x = (int)f2bf(x0.x) | ((int)f2bf(x0.y) << 16);
            o.y = (int)f2bf(x0.z) | ((int)f2bf(x0.w) << 16);
            o.z = (int)f2bf(x1.x) | ((int)f2bf(x1.y) << 16);
            o.w = (int)f2bf(x1.z) | ((int)f2bf(x1.w) << 16);
            reinterpret_cast<int4*>(Wmb + ((size_t)de * 2 + half) * 8)[0] = o;
        }
        return;
    }

    const int mblk = blk / NKT;
    if (blk == 0) {
        for (int i = t; i < MPAD; i += 256) {
            float s = 0.f, b = 0.f;
            if (i < 512) {
                s = bn_p_g[i] / sqrtf(bn_p_v[i] + 1e-5f);
                b = bn_p_b[i] - bn_p_m[i] * s;
            } else if (i < 544) {
                const int j = i - 512;
                s = bn_a_g[j] / sqrtf(bn_a_v[j] + 1e-5f);
                b = bn_a_b[j] - bn_a_m[j] * s;
            }
            sc[i] = s; bi[i] = b;
        }
    }

    const int kt = blk - mblk * NKT;
    #pragma unroll
    for (int j = 0; j < 8; ++j) {
        const int c = t + j * 256;               // 0..2047
        const int kc8 = c >> 7, slot = c & 127;
        const int row = mblk * 128 + (slot ^ (kc8 << 2));
        const int k0 = (kt * 16 + kc8) * 8;
        float v[8] = {0.f,0.f,0.f,0.f,0.f,0.f,0.f,0.f};
        if (row < 512) {
            const float4* s4 = reinterpret_cast<const float4*>(w_pose + (size_t)row * KDIM + k0);
            float4 x0 = s4[0], x1 = s4[1];
            v[0]=x0.x; v[1]=x0.y; v[2]=x0.z; v[3]=x0.w;
            v[4]=x1.x; v[5]=x1.y; v[6]=x1.z; v[7]=x1.w;
        } else if (row < 544) {
            const float4* s4 = reinterpret_cast<const float4*>(w_a + (size_t)(row - 512) * KDIM + k0);
            float4 x0 = s4[0], x1 = s4[1];
            v[0]=x0.x; v[1]=x0.y; v[2]=x0.z; v[3]=x0.w;
            v[4]=x1.x; v[5]=x1.y; v[6]=x1.z; v[7]=x1.w;
        }
        int4 o;
        o.x = (int)f2bf(v[0]) | ((int)f2bf(v[1]) << 16);
        o.y = (int)f2bf(v[2]) | ((int)f2bf(v[3]) << 16);
        o.z = (int)f2bf(v[4]) | ((int)f2bf(v[5]) << 16);
        o.w = (int)f2bf(v[6]) | ((int)f2bf(v[7]) << 16);
        reinterpret_cast<int4*>(At + ((((size_t)blk) << 11) + c) * 8)[0] = o;
    }
}

// ---------------------------------------------------------------------------
// pack_b: im2col fp32->bf16, pre-tiled, px-major work order (R10 win).
// ---------------------------------------------------------------------------
__global__ __launch_bounds__(1024) void pack_b_kernel(
    const float* __restrict__ x, unsigned short* __restrict__ Bt)
{
    __shared__ __align__(16) float xs[CIN * 25];
    const int b = blockIdx.x;
    const int t = threadIdx.x;
    const float4* xb = reinterpret_cast<const float4*>(x + (size_t)b * (CIN * 25));
    for (int f4 = t; f4 < (CIN * 25) / 4; f4 += 1024)
        reinterpret_cast<float4*>(xs)[f4] = xb[f4];
    __syncthreads();

    for (int w = t; w < 25 * (KDIM / 8); w += 1024) {
        const int ch = w / 25;                   // k-chunk (px-major order)
        const int px = w - ch * 25;
        const int py = px / 5, qx = px % 5;
        const int k0 = ch * 8;
        unsigned short v[8];
        #pragma unroll
        for (int j = 0; j < 8; ++j) {
            const int k = k0 + j;
            const int ci = k / 9;
            const int kk = k - ci * 9;
            const int dy = kk / 3, dx = kk - dy * 3;
            const int yy = py + dy - 1, xx = qx + dx - 1;
            const bool ok = (yy >= 0) & (yy < 5) & (xx >= 0) & (xx < 5);
            v[j] = ok ? f2bf(xs[ci * 25 + yy * 5 + xx]) : (unsigned short)0;
        }
        int4 o;
        o.x = (int)v[0] | ((int)v[1] << 16);
        o.y = (int)v[2] | ((int)v[3] << 16);
        o.z = (int)v[4] | ((int)v[5] << 16);
        o.w = (int)v[6] | ((int)v[7] << 16);
        const int n = b * 25 + px;
        const int nblk = n >> 7, nr = n & 127;
        const int kt = k0 >> 7;
        const int kc8 = (k0 >> 3) & 15;
        const int c = kc8 * 128 + (nr ^ (kc8 << 2));
        reinterpret_cast<int4*>(Bt + ((((size_t)(nblk * NKT + kt)) << 11) + c) * 8)[0] = o;
    }
}

// ---------------------------------------------------------------------------
// gemm: R11 shape (1024 threads = 4 K-groups x (2x2) waves, 64x64 wave tile,
// BK=128 double-buffered, XCD-swizzled grid, bf16 Cp / fp32 Ca split).
// ---------------------------------------------------------------------------
__global__ __launch_bounds__(1024) void gemm_kernel(
    const unsigned short* __restrict__ At,
    const unsigned short* __restrict__ Bt,
    const float* __restrict__ sc, const float* __restrict__ bi,
    unsigned short* __restrict__ Cp,        // [512][6400] bf16
    float* __restrict__ Ca)                 // [32][6400] fp32
{
    __shared__ __align__(16) unsigned char smem[131072];
    const int t = threadIdx.x;
    const int L = blockIdx.x;
    int mblk, nblk;
    if (L >= 240) { const int i = L - 240; mblk = i >> 1; nblk = 48 + (i & 1); }
    else          { const int q = L / 40, r = L - q * 40;
                    mblk = r >> 3; nblk = q * 8 + (r & 7); }
    const int m0 = mblk * 128, n0 = nblk * 128;
    const int lane = t & 63, w = t >> 6;
    const int g = w >> 2, wq = w & 3;          // 4 K-groups x 4 tile-waves
    const int wm = wq >> 1, wn = wq & 1;
    const int row16 = lane & 15, quad = lane >> 4;

    f32x4 acc[4][4] = {};

    const unsigned short* gAbase = At + (((size_t)mblk * NKT) << 14);
    const unsigned short* gBbase = Bt + (((size_t)nblk * NKT) << 14);

    #define STAGE(kt, s)                                                      \
    {                                                                         \
        unsigned short* As_ = (unsigned short*)(smem + (s) * 65536);          \
        unsigned short* Bs_ = As_ + 16384;                                    \
        const unsigned short* ga = gAbase + ((size_t)(kt) << 14);             \
        const unsigned short* gb = gBbase + ((size_t)(kt) << 14);             \
        _Pragma("unroll")                                                     \
        for (int j = 0; j < 2; ++j) {                                         \
            async_copy16(ga + ((size_t)(j * 1024 + t) << 3),                  \
                         As_ + ((size_t)(j * 1024 + w * 64) << 3));           \
            async_copy16(gb + ((size_t)(j * 1024 + t) << 3),                  \
                         Bs_ + ((size_t)(j * 1024 + w * 64) << 3));           \
        }                                                                     \
    }

    #define COMPUTE(s)                                                        \
    {                                                                         \
        const unsigned short* As_ = (const unsigned short*)(smem + (s) * 65536);\
        const unsigned short* Bs_ = As_ + 16384;                              \
        const int kc8b = g * 4 + quad;                                        \
        const int sw = kc8b << 2;                                             \
        bf16x8 af[4], bfr[4];                                                 \
        _Pragma("unroll")                                                     \
        for (int mt = 0; mt < 4; ++mt)                                        \
            af[mt] = *reinterpret_cast<const bf16x8*>(                        \
                &As_[(size_t)(kc8b * 128 + ((wm * 64 + mt * 16 + row16) ^ sw)) * 8]);\
        _Pragma("unroll")                                                     \
        for (int nt = 0; nt < 4; ++nt)                                        \
            bfr[nt] = *reinterpret_cast<const bf16x8*>(                       \
                &Bs_[(size_t)(kc8b * 128 + ((wn * 64 + nt * 16 + row16) ^ sw)) * 8]);\
        _Pragma("unroll")                                                     \
        for (int mt = 0; mt < 4; ++mt)                                        \
            _Pragma("unroll")                                                 \
            for (int nt = 0; nt < 4; ++nt)                                    \
                acc[mt][nt] = __builtin_amdgcn_mfma_f32_16x16x32_bf16(        \
                    af[mt], bfr[nt], acc[mt][nt], 0, 0, 0);                   \
    }

    STAGE(0, 0);
    for (int kt = 0; kt < NKT; ++kt) {
        __syncthreads();
        if (kt + 1 < NKT) STAGE(kt + 1, (kt + 1) & 1);
        COMPUTE(kt & 1);
    }
    #undef STAGE
    #undef COMPUTE

    // merge the 4 K-groups into group 0 (3 rounds through 64 KB of LDS)
    f32x4* mb = (f32x4*)smem;                 // 4096 f32x4 slots
    #pragma unroll
    for (int r = 1; r < 4; ++r) {
        __syncthreads();
        if (g == r) {
            f32x4* dst = mb + wq * 1024;
            #pragma unroll
            for (int i = 0; i < 16; ++i)
                dst[i * 64 + lane] = acc[i >> 2][i & 3];
        }
        __syncthreads();
        if (g == 0) {
            const f32x4* src = mb + wq * 1024;
            #pragma unroll
            for (int i = 0; i < 16; ++i)
                acc[i >> 2][i & 3] += src[i * 64 + lane];
        }
    }

    if (g == 0) {
        #pragma unroll
        for (int mt = 0; mt < 4; ++mt) {
            const int mbase = m0 + wm * 64 + mt * 16 + quad * 4;
            if (mbase >= 544) continue;
            #pragma unroll
            for (int rg = 0; rg < 4; ++rg) {
                const int m = mbase + rg;
                const float s = sc[m], bbx = bi[m];
                #pragma unroll
                for (int nt = 0; nt < 4; ++nt) {
                    const int n = n0 + wn * 64 + nt * 16 + row16;
                    const float v = fmaf(acc[mt][nt][rg], s, bbx);
                    if (m < 512) Cp[(size_t)m * NTOT + n] = f2bf(v);
                    else Ca[(size_t)(m - 512) * NTOT + n] = 1.f / (1.f + fexp(-v));
                }
            }
        }
    }
}

// ---------------------------------------------------------------------------
// EM routing — R23: R21 structure (640 thr, wave=class, bf16 psh, shfl-merged
// q, dedup'd in-place softmax, register-prefetched bf16 W — reproduced
// twice at 75.4-75.7 us) with the hot-loop arithmetic re-expressed as
// PACKED f32 pairs (ext_vector_type(2)): vote = 16 pk_fma instead of 32
// scalar; q-accum and S1/S2 stats paired likewise. gfx950's 157 TF fp32
// peak is v_pk_*_f32 (2 floats/issue slot); R21's loop was all-scalar.
// The bf16 unpack already yields natural (lo,hi) f32 pairs per dword, so
// pairing costs no data movement. Same live values (just paired) -> same
// ~72-VGPR profile, same memory behavior: none of the four refuted traps
// (960-thr RA cap, added-state spill, LDS barrier drain, f32-W L2 thrash,
// R22's pair-rendezvous cost) applies. Only numeric change: q's 8-term
// chain becomes 2x4-term + combine (fp32 reassociation, << bf16 absmax).
// Downside bound: if the backend scalarizes, perf == R21.
// ---------------------------------------------------------------------------
__global__ __launch_bounds__(640, 1) void em_kernel(
    const unsigned short* __restrict__ Cp,    // [512][6400] bf16 pose
    const float* __restrict__ Ca,             // [32][6400] fp32 activations
    const unsigned short* __restrict__ Wmb,   // [25][10][32][16] bf16
    const float* __restrict__ beta_u, const float* __restrict__ beta_a,
    float* __restrict__ out)                  // (256,10)
{
    __shared__ __align__(16) unsigned short psh[25][2][32][8]; // 25.6 KB bf16 pose
    __shared__ float aush[800];                                // 3.2 KB
    __shared__ float lnq[NCLS][800];                           // 32 KB ln_p, reused as rw
    __shared__ float mu_sh[NCLS][16];
    __shared__ float i2s_sh[NCLS][16];
    __shared__ float costp[2][NCLS];
    __shared__ float slgp[2][NCLS];
    __shared__ float Kc_sh[NCLS];
    __shared__ float aout_sh[NCLS];

    const int b = blockIdx.x, t = threadIdx.x;
    const int c = t >> 6;                     // wave = class
    const int rh = (t >> 5) & 1;              // half-wave = pose-dim half
    const int a = t & 31;                     // capsule lane

    // stage pose bf16: Cp[c2][b*25+px] -> psh[px][(c2&15)>>3][c2>>4][c2&7]
    const unsigned short* pb = Cp + (size_t)b * 25;
    for (int f = t; f < 12800; f += 640) {
        const int c2 = f / 25, px = f - c2 * 25;
        const int e = c2 & 15;
        psh[px][e >> 3][c2 >> 4][e & 7] = pb[(size_t)c2 * NTOT + px];
    }
    const float* ab = Ca + (size_t)b * 25;
    for (int f = t; f < 800; f += 640) {
        const int ci = f / 25, px = f - ci * 25;
        aush[px * 32 + ci] = ab[(size_t)ci * NTOT + px];
    }
    __syncthreads();

    const float bu = beta_u[c], ba = beta_a[c];
    f32x2 mu2[4], ni2s2[4];                   // paired mu / NEGATED 0.5/sg
    float KcL = 0.f;
    const unsigned short* wbase = Wmb + ((size_t)(c * 32 + a)) * 16;  // + kk*5120

    // unpack 16 bf16 W + 8 bf16 pose into f32x2 pairs; 16 packed FMA vote.
    // vv2[jp] holds (vv[2jp], vv[2jp+1]): jp= jr*2+p covers s=2p,2p+1 of row jr.
    #define VOTE(w0_, w1_, p_, vv2)                                          \
        {                                                                    \
            float pm[8];                                                     \
            const unsigned int pu[4] = {(unsigned)p_.x, (unsigned)p_.y,      \
                                        (unsigned)p_.z, (unsigned)p_.w};     \
            _Pragma("unroll")                                                \
            for (int i = 0; i < 4; ++i) {                                    \
                pm[2*i]   = __uint_as_float(pu[i] << 16);                    \
                pm[2*i+1] = __uint_as_float(pu[i] & 0xFFFF0000u);            \
            }                                                                \
            const unsigned int uu[8] = {(unsigned)w0_.x,(unsigned)w0_.y,     \
                (unsigned)w0_.z,(unsigned)w0_.w,(unsigned)w1_.x,             \
                (unsigned)w1_.y,(unsigned)w1_.z,(unsigned)w1_.w};            \
            f32x2 wv2[8];                                                    \
            _Pragma("unroll")                                                \
            for (int i = 0; i < 8; ++i) {                                    \
                wv2[i].x = __uint_as_float(uu[i] << 16);                     \
                wv2[i].y = __uint_as_float(uu[i] & 0xFFFF0000u);             \
            }                                                                \
            _Pragma("unroll")                                                \
            for (int jr = 0; jr < 2; ++jr) {                                 \
                _Pragma("unroll")                                            \
                for (int pp = 0; pp < 2; ++pp) {                             \
                    f32x2 acc2 = {0.f, 0.f};                                 \
                    _Pragma("unroll")                                        \
                    for (int tt = 0; tt < 4; ++tt)                           \
                        acc2 = (f32x2)(pm[jr*4+tt]) * wv2[tt*2+pp] + acc2;   \
                    vv2[jr*2+pp] = acc2;                                     \
                }                                                            \
            }                                                                \
        }

    float p95 = 1.f;
    for (int it = 0; it < 3; ++it) {
        p95 *= 0.95f;
        const float lam = 0.01f * (1.f - p95);

        if (it > 0) {
            // ---- phase A: ln_p, W depth-1 + pose depth-1 prefetch;
            //      packed q-accum; halves merged via shfl_xor(32) ----
            int4 wr0 = *reinterpret_cast<const int4*>(wbase);
            int4 wr1 = *reinterpret_cast<const int4*>(wbase + 8);
            int4 pr  = *reinterpret_cast<const int4*>(&psh[0][rh][a][0]);
            for (int kk = 0; kk < 25; ++kk) {
                const int4 w0 = wr0, w1 = wr1, p = pr;
                if (kk < 24) {
                    const unsigned short* wn = wbase + (size_t)(kk + 1) * 5120;
                    wr0 = *reinterpret_cast<const int4*>(wn);
                    wr1 = *reinterpret_cast<const int4*>(wn + 8);
                    pr  = *reinterpret_cast<const int4*>(&psh[kk + 1][rh][a][0]);
                }
                f32x2 vv2[4];
                VOTE(w0, w1, p, vv2);
                f32x2 q2 = {0.f, 0.f};
                #pragma unroll
                for (int jp = 0; jp < 4; ++jp) {
                    const f32x2 d2 = vv2[jp] - mu2[jp];
                    q2 = (d2 * d2) * ni2s2[jp] + q2;
                }
                float q = q2.x + q2.y + ((rh == 0) ? KcL : 0.f);
                q += __shfl_xor(q, 32);
                if (rh == 0) lnq[c][kk * 32 + a] = q;
            }
            __syncthreads();
            // ---- phase R (dedup, in-place): one thread per m does the
            //      class softmax once; rw overwrites lnq ----
            for (int m = t; m < 800; m += 640) {
                float qv[NCLS];
                #pragma unroll
                for (int cc = 0; cc < NCLS; ++cc) qv[cc] = lnq[cc][m];
                float mx = qv[0];
                #pragma unroll
                for (int cc = 1; cc < NCLS; ++cc) mx = fmaxf(mx, qv[cc]);
                float ev[NCLS];
                float den = 0.f;
                #pragma unroll
                for (int cc = 0; cc < NCLS; ++cc) {
                    ev[cc] = fexp(qv[cc] - mx);
                    den += ev[cc];
                }
                const float s = aush[m] * __builtin_amdgcn_rcpf(den);
                #pragma unroll
                for (int cc = 0; cc < NCLS; ++cc)
                    lnq[cc][m] = ev[cc] * s;
            }
            __syncthreads();
        }

        // ---- phase S: weighted stats (packed), W depth-2 + pose depth-1 ----
        float S0 = 0.f;
        f32x2 S12[4], S22[4];
        #pragma unroll
        for (int jp = 0; jp < 4; ++jp) { S12[jp] = (f32x2){0.f, 0.f};
                                         S22[jp] = (f32x2){0.f, 0.f}; }

        int4 wA0 = *reinterpret_cast<const int4*>(wbase);
        int4 wA1 = *reinterpret_cast<const int4*>(wbase + 8);
        int4 wB0 = *reinterpret_cast<const int4*>(wbase + 5120);
        int4 wB1 = *reinterpret_cast<const int4*>(wbase + 5120 + 8);
        int4 pr  = *reinterpret_cast<const int4*>(&psh[0][rh][a][0]);
        for (int kk = 0; kk < 25; ++kk) {
            const int4 w0 = wA0, w1 = wA1, p = pr;
            wA0 = wB0; wA1 = wB1;
            if (kk < 23) {
                const unsigned short* wn = wbase + (size_t)(kk + 2) * 5120;
                wB0 = *reinterpret_cast<const int4*>(wn);
                wB1 = *reinterpret_cast<const int4*>(wn + 8);
            }
            if (kk < 24)
                pr = *reinterpret_cast<const int4*>(&psh[kk + 1][rh][a][0]);
            f32x2 vv2[4];
            VOTE(w0, w1, p, vv2);
            const int m = kk * 32 + a;
            const float rw = (it == 0) ? aush[m] : lnq[c][m];
            S0 += rw;
            const f32x2 rw2 = (f32x2)(rw);
            #pragma unroll
            for (int jp = 0; jp < 4; ++jp) {
                const f32x2 rv2 = rw2 * vv2[jp];
                S12[jp] = S12[jp] + rv2;
                S22[jp] = rv2 * vv2[jp] + S22[jp];
            }
        }

        // unpack pairs, butterfly over the 32 a-lanes (within half-wave)
        float S1[8], S2[8];
        #pragma unroll
        for (int jp = 0; jp < 4; ++jp) {
            S1[2*jp] = S12[jp].x; S1[2*jp+1] = S12[jp].y;
            S2[2*jp] = S22[jp].x; S2[2*jp+1] = S22[jp].y;
        }
        #pragma unroll
        for (int off = 16; off >= 1; off >>= 1) {
            S0 += __shfl_xor(S0, off);
            #pragma unroll
            for (int j = 0; j < 8; ++j) {
                S1[j] += __shfl_xor(S1[j], off);
                S2[j] += __shfl_xor(S2[j], off);
            }
        }

        // per-half epilogue (both rh halves hold the SAME full S0)
        if (a == 0) {
            const float s0e = S0 + 1e-12f;
            const float inv = 1.f / s0e;
            float cost_ = 0.f, slg_ = 0.f;
            #pragma unroll
            for (int j = 0; j < 8; ++j) {
                const float mu_ = S1[j] * inv;
                const float sg = (S2[j] - 2.f * mu_ * S1[j] + mu_ * mu_ * S0) * inv
                                 + 1e-12f;
                cost_ += bu + 0.5f * flog(sg);
                slg_ += flog(sg * LN2PI_F);
                mu_sh[c][rh * 8 + j] = mu_;
                i2s_sh[c][rh * 8 + j] = 0.5f / sg;
            }
            costp[rh][c] = cost_;
            slgp[rh][c] = slg_;
        }
        __syncthreads();
        if (a == 0 && rh == 0) {
            const float costsum = (costp[0][c] + costp[1][c]) * S0;
            const float aout = 1.f / (1.f + fexp(-(lam * (ba - costsum))));
            aout_sh[c] = aout;
            Kc_sh[c] = flog(aout) - 0.5f * (slgp[0][c] + slgp[1][c]);
        }
        __syncthreads();
        if (it < 2) {
            #pragma unroll
            for (int jp = 0; jp < 4; ++jp) {
                mu2[jp].x = mu_sh[c][rh * 8 + 2*jp];
                mu2[jp].y = mu_sh[c][rh * 8 + 2*jp + 1];
                ni2s2[jp].x = -i2s_sh[c][rh * 8 + 2*jp];
                ni2s2[jp].y = -i2s_sh[c][rh * 8 + 2*jp + 1];
            }
            KcL = Kc_sh[c];
        }
    }

    if (t < NCLS) {
        float s = 0.f;
        #pragma unroll
        for (int cc = 0; cc < NCLS; ++cc) s += aout_sh[cc];
        out[b * NCLS + t] = flog(aout_sh[t] / s);
    }
    #undef VOTE
}

// ---------------------------------------------------------------------------
extern "C" void kernel_launch(void* const* d_in, const int* in_sizes, int n_in,
                              void* d_out, int out_size, void* d_ws, size_t ws_size,
                              hipStream_t stream) {
    const float* x      = (const float*)d_in[0];
    const float* w_a    = (const float*)d_in[1];
    const float* w_pose = (const float*)d_in[2];
    const float* bn_a_g = (const float*)d_in[3];
    const float* bn_a_b = (const float*)d_in[4];
    const float* bn_a_m = (const float*)d_in[5];
    const float* bn_a_v = (const float*)d_in[6];
    const float* bn_p_g = (const float*)d_in[7];
    const float* bn_p_b = (const float*)d_in[8];
    const float* bn_p_m = (const float*)d_in[9];
    const float* bn_p_v = (const float*)d_in[10];
    const float* Wm     = (const float*)d_in[11];
    const float* beta_u = (const float*)d_in[12];
    const float* beta_a = (const float*)d_in[13];
    float* out = (float*)d_out;

    char* p = (char*)d_ws;
    unsigned short* At  = (unsigned short*)p;  p += (size_t)MPAD * KDIM * 2;
    unsigned short* Bt  = (unsigned short*)p;  p += (size_t)NTOT * KDIM * 2;
    unsigned short* Wmb = (unsigned short*)p;  p += (size_t)800 * NCLS * 16 * 2;
    unsigned short* Cp  = (unsigned short*)p;  p += (size_t)512 * NTOT * 2;
    float* Ca = (float*)p;                     p += (size_t)32 * NTOT * 4;
    float* sc = (float*)p;                     p += MPAD * 4;
    float* bi = (float*)p;                     p += MPAD * 4;

    pack_a_kernel<<<NABLK + 63, 256, 0, stream>>>(w_pose, w_a,
                                                  bn_p_g, bn_p_b, bn_p_m, bn_p_v,
                                                  bn_a_g, bn_a_b, bn_a_m, bn_a_v,
                                                  Wm, At, Wmb, sc, bi);
    pack_b_kernel<<<256, 1024, 0, stream>>>(x, Bt);
    gemm_kernel<<<250, 1024, 0, stream>>>(At, Bt, sc, bi, Cp, Ca);
    em_kernel<<<256, 640, 0, stream>>>(Cp, Ca, Wmb, beta_u, beta_a, out);
}

// Round 13
// 227.028 us; speedup vs baseline: 1.2551x; 1.0006x over previous
//
#include <hip/hip_runtime.h>
#include <math.h>

#define CIN 512
#define NCLS 10
#define KDIM 4608            // 512*9
#define NTOT 6400            // 256*25
#define MPAD 640
#define BK 128
#define NKT 36               // KDIM/BK
#define NABLK (5 * NKT)      // 180 A-tile blocks in pack_a
#define LN2PI_F 1.8378770664093453f

typedef __attribute__((ext_vector_type(8))) short bf16x8;
typedef __attribute__((ext_vector_type(4))) float f32x4;

typedef const __attribute__((address_space(1))) void* gas_ptr;
typedef __attribute__((address_space(3))) void* las_ptr;

__device__ __forceinline__ void async_copy16(const void* g, void* l) {
    __builtin_amdgcn_global_load_lds((gas_ptr)g, (las_ptr)l, 16, 0, 0);
}

__device__ __forceinline__ unsigned short f2bf(float f) {
    unsigned int u = __float_as_uint(f);
    u = (u + 0x7fffu + ((u >> 16) & 1u)) >> 16;   // RNE
    return (unsigned short)u;
}
__device__ __forceinline__ float bf2f(unsigned short s) {
    return __uint_as_float(((unsigned int)s) << 16);
}
__device__ __forceinline__ float fexp(float x) { return __expf(x); }
__device__ __forceinline__ float flog(float x) { return __logf(x); }

// ---------------------------------------------------------------------------
// pack_a: blocks [0,180): weights fp32 -> bf16 pre-tiled for the GEMM's LDS
// staging order. Blocks [180, 243): Wm fp32 -> bf16, RE-LAYOUT for em:
// dst entry (kk*10 + c)*32 + a  <-  src entry m*10 + c (m = kk*32+a).
// Block 0 additionally computes the folded BN scale/bias.
// Wmb must stay bf16 (R20: f32 W thrashed L2 — FETCH 13->337 MB; the 1 MB
// bf16 footprint is what keeps W L2-resident across 32 blocks/XCD).
// ---------------------------------------------------------------------------
__global__ __launch_bounds__(256) void pack_a_kernel(
    const float* __restrict__ w_pose, const float* __restrict__ w_a,
    const float* __restrict__ bn_p_g, const float* __restrict__ bn_p_b,
    const float* __restrict__ bn_p_m, const float* __restrict__ bn_p_v,
    const float* __restrict__ bn_a_g, const float* __restrict__ bn_a_b,
    const float* __restrict__ bn_a_m, const float* __restrict__ bn_a_v,
    const float* __restrict__ Wm,
    unsigned short* __restrict__ At, unsigned short* __restrict__ Wmb,
    float* __restrict__ sc, float* __restrict__ bi)
{
    const int blk = blockIdx.x;
    const int t = threadIdx.x;

    if (blk >= NABLK) {                          // ---- Wm bf16 packing ----
        const int chunk = (blk - NABLK) * 256 + t;   // 8 floats per chunk
        if (chunk < 16000) {
            const int e = chunk >> 1, half = chunk & 1;   // entry = (m,c), 16 floats
            const int m = e / 10, c = e - m * 10;
            const int kk = m >> 5, a = m & 31;
            const int de = (kk * 10 + c) * 32 + a;        // transposed entry
            const float4* s4 = reinterpret_cast<const float4*>(Wm + (size_t)chunk * 8);
            float4 x0 = s4[0], x1 = s4[1];
            int4 o;
            o.x = (int)f2bf(x0.x) | ((int)f2bf(x0.y) << 16);
            o.y = (int)f2bf(x0.z) | ((int)f2bf(x0.w) << 16);
            o.z = (int)f2bf(x1.x) | ((int)f2bf(x1.y) << 16);
            o.w = (int)f2bf(x1.z) | ((int)f2bf(x1.w) << 16);
            reinterpret_cast<int4*>(Wmb + ((size_t)de * 2 + half) * 8)[0] = o;
        }
        return;
    }

    const int mblk = blk / NKT;
    if (blk == 0) {
        for (int i = t; i < MPAD; i += 256) {
            float s = 0.f, b = 0.f;
            if (i < 512) {
                s = bn_p_g[i] / sqrtf(bn_p_v[i] + 1e-5f);
                b = bn_p_b[i] - bn_p_m[i] * s;
            } else if (i < 544) {
                const int j = i - 512;
                s = bn_a_g[j] / sqrtf(bn_a_v[j] + 1e-5f);
                b = bn_a_b[j] - bn_a_m[j] * s;
            }
            sc[i] = s; bi[i] = b;
        }
    }

    const int kt = blk - mblk * NKT;
    #pragma unroll
    for (int j = 0; j < 8; ++j) {
        const int c = t + j * 256;               // 0..2047
        const int kc8 = c >> 7, slot = c & 127;
        const int row = mblk * 128 + (slot ^ (kc8 << 2));
        const int k0 = (kt * 16 + kc8) * 8;
        float v[8] = {0.f,0.f,0.f,0.f,0.f,0.f,0.f,0.f};
        if (row < 512) {
            const float4* s4 = reinterpret_cast<const float4*>(w_pose + (size_t)row * KDIM + k0);
            float4 x0 = s4[0], x1 = s4[1];
            v[0]=x0.x; v[1]=x0.y; v[2]=x0.z; v[3]=x0.w;
            v[4]=x1.x; v[5]=x1.y; v[6]=x1.z; v[7]=x1.w;
        } else if (row < 544) {
            const float4* s4 = reinterpret_cast<const float4*>(w_a + (size_t)(row - 512) * KDIM + k0);
            float4 x0 = s4[0], x1 = s4[1];
            v[0]=x0.x; v[1]=x0.y; v[2]=x0.z; v[3]=x0.w;
            v[4]=x1.x; v[5]=x1.y; v[6]=x1.z; v[7]=x1.w;
        }
        int4 o;
        o.x = (int)f2bf(v[0]) | ((int)f2bf(v[1]) << 16);
        o.y = (int)f2bf(v[2]) | ((int)f2bf(v[3]) << 16);
        o.z = (int)f2bf(v[4]) | ((int)f2bf(v[5]) << 16);
        o.w = (int)f2bf(v[6]) | ((int)f2bf(v[7]) << 16);
        reinterpret_cast<int4*>(At + ((((size_t)blk) << 11) + c) * 8)[0] = o;
    }
}

// ---------------------------------------------------------------------------
// pack_b: im2col fp32->bf16, pre-tiled, px-major work order (R10 win).
// ---------------------------------------------------------------------------
__global__ __launch_bounds__(1024) void pack_b_kernel(
    const float* __restrict__ x, unsigned short* __restrict__ Bt)
{
    __shared__ __align__(16) float xs[CIN * 25];
    const int b = blockIdx.x;
    const int t = threadIdx.x;
    const float4* xb = reinterpret_cast<const float4*>(x + (size_t)b * (CIN * 25));
    for (int f4 = t; f4 < (CIN * 25) / 4; f4 += 1024)
        reinterpret_cast<float4*>(xs)[f4] = xb[f4];
    __syncthreads();

    for (int w = t; w < 25 * (KDIM / 8); w += 1024) {
        const int ch = w / 25;                   // k-chunk (px-major order)
        const int px = w - ch * 25;
        const int py = px / 5, qx = px % 5;
        const int k0 = ch * 8;
        unsigned short v[8];
        #pragma unroll
        for (int j = 0; j < 8; ++j) {
            const int k = k0 + j;
            const int ci = k / 9;
            const int kk = k - ci * 9;
            const int dy = kk / 3, dx = kk - dy * 3;
            const int yy = py + dy - 1, xx = qx + dx - 1;
            const bool ok = (yy >= 0) & (yy < 5) & (xx >= 0) & (xx < 5);
            v[j] = ok ? f2bf(xs[ci * 25 + yy * 5 + xx]) : (unsigned short)0;
        }
        int4 o;
        o.x = (int)v[0] | ((int)v[1] << 16);
        o.y = (int)v[2] | ((int)v[3] << 16);
        o.z = (int)v[4] | ((int)v[5] << 16);
        o.w = (int)v[6] | ((int)v[7] << 16);
        const int n = b * 25 + px;
        const int nblk = n >> 7, nr = n & 127;
        const int kt = k0 >> 7;
        const int kc8 = (k0 >> 3) & 15;
        const int c = kc8 * 128 + (nr ^ (kc8 << 2));
        reinterpret_cast<int4*>(Bt + ((((size_t)(nblk * NKT + kt)) << 11) + c) * 8)[0] = o;
    }
}

// ---------------------------------------------------------------------------
// gemm: R11 shape (1024 threads = 4 K-groups x (2x2) waves, 64x64 wave tile,
// BK=128 double-buffered, XCD-swizzled grid, bf16 Cp / fp32 Ca split).
// ---------------------------------------------------------------------------
__global__ __launch_bounds__(1024) void gemm_kernel(
    const unsigned short* __restrict__ At,
    const unsigned short* __restrict__ Bt,
    const float* __restrict__ sc, const float* __restrict__ bi,
    unsigned short* __restrict__ Cp,        // [512][6400] bf16
    float* __restrict__ Ca)                 // [32][6400] fp32
{
    __shared__ __align__(16) unsigned char smem[131072];
    const int t = threadIdx.x;
    const int L = blockIdx.x;
    int mblk, nblk;
    if (L >= 240) { const int i = L - 240; mblk = i >> 1; nblk = 48 + (i & 1); }
    else          { const int q = L / 40, r = L - q * 40;
                    mblk = r >> 3; nblk = q * 8 + (r & 7); }
    const int m0 = mblk * 128, n0 = nblk * 128;
    const int lane = t & 63, w = t >> 6;
    const int g = w >> 2, wq = w & 3;          // 4 K-groups x 4 tile-waves
    const int wm = wq >> 1, wn = wq & 1;
    const int row16 = lane & 15, quad = lane >> 4;

    f32x4 acc[4][4] = {};

    const unsigned short* gAbase = At + (((size_t)mblk * NKT) << 14);
    const unsigned short* gBbase = Bt + (((size_t)nblk * NKT) << 14);

    #define STAGE(kt, s)                                                      \
    {                                                                         \
        unsigned short* As_ = (unsigned short*)(smem + (s) * 65536);          \
        unsigned short* Bs_ = As_ + 16384;                                    \
        const unsigned short* ga = gAbase + ((size_t)(kt) << 14);             \
        const unsigned short* gb = gBbase + ((size_t)(kt) << 14);             \
        _Pragma("unroll")                                                     \
        for (int j = 0; j < 2; ++j) {                                         \
            async_copy16(ga + ((size_t)(j * 1024 + t) << 3),                  \
                         As_ + ((size_t)(j * 1024 + w * 64) << 3));           \
            async_copy16(gb + ((size_t)(j * 1024 + t) << 3),                  \
                         Bs_ + ((size_t)(j * 1024 + w * 64) << 3));           \
        }                                                                     \
    }

    #define COMPUTE(s)                                                        \
    {                                                                         \
        const unsigned short* As_ = (const unsigned short*)(smem + (s) * 65536);\
        const unsigned short* Bs_ = As_ + 16384;                              \
        const int kc8b = g * 4 + quad;                                        \
        const int sw = kc8b << 2;                                             \
        bf16x8 af[4], bfr[4];                                                 \
        _Pragma("unroll")                                                     \
        for (int mt = 0; mt < 4; ++mt)                                        \
            af[mt] = *reinterpret_cast<const bf16x8*>(                        \
                &As_[(size_t)(kc8b * 128 + ((wm * 64 + mt * 16 + row16) ^ sw)) * 8]);\
        _Pragma("unroll")                                                     \
        for (int nt = 0; nt < 4; ++nt)                                        \
            bfr[nt] = *reinterpret_cast<const bf16x8*>(                       \
                &Bs_[(size_t)(kc8b * 128 + ((wn * 64 + nt * 16 + row16) ^ sw)) * 8]);\
        _Pragma("unroll")                                                     \
        for (int mt = 0; mt < 4; ++mt)                                        \
            _Pragma("unroll")                                                 \
            for (int nt = 0; nt < 4; ++nt)                                    \
                acc[mt][nt] = __builtin_amdgcn_mfma_f32_16x16x32_bf16(        \
                    af[mt], bfr[nt], acc[mt][nt], 0, 0, 0);                   \
    }

    STAGE(0, 0);
    for (int kt = 0; kt < NKT; ++kt) {
        __syncthreads();
        if (kt + 1 < NKT) STAGE(kt + 1, (kt + 1) & 1);
        COMPUTE(kt & 1);
    }
    #undef STAGE
    #undef COMPUTE

    // merge the 4 K-groups into group 0 (3 rounds through 64 KB of LDS)
    f32x4* mb = (f32x4*)smem;                 // 4096 f32x4 slots
    #pragma unroll
    for (int r = 1; r < 4; ++r) {
        __syncthreads();
        if (g == r) {
            f32x4* dst = mb + wq * 1024;
            #pragma unroll
            for (int i = 0; i < 16; ++i)
                dst[i * 64 + lane] = acc[i >> 2][i & 3];
        }
        __syncthreads();
        if (g == 0) {
            const f32x4* src = mb + wq * 1024;
            #pragma unroll
            for (int i = 0; i < 16; ++i)
                acc[i >> 2][i & 3] += src[i * 64 + lane];
        }
    }

    if (g == 0) {
        #pragma unroll
        for (int mt = 0; mt < 4; ++mt) {
            const int mbase = m0 + wm * 64 + mt * 16 + quad * 4;
            if (mbase >= 544) continue;
            #pragma unroll
            for (int rg = 0; rg < 4; ++rg) {
                const int m = mbase + rg;
                const float s = sc[m], bbx = bi[m];
                #pragma unroll
                for (int nt = 0; nt < 4; ++nt) {
                    const int n = n0 + wn * 64 + nt * 16 + row16;
                    const float v = fmaf(acc[mt][nt][rg], s, bbx);
                    if (m < 512) Cp[(size_t)m * NTOT + n] = f2bf(v);
                    else Ca[(size_t)(m - 512) * NTOT + n] = 1.f / (1.f + fexp(-v));
                }
            }
        }
    }
}

// ---------------------------------------------------------------------------
// EM routing — R24 FINAL: exact R21/R17 structure (best verified: em
// 75.4-75.7 us, reproduced twice; VGPR 72, zero spill). 640 threads =
// wave-per-class x rh half-wave x 32 a-lanes; bf16 psh [25][2][32][8]
// (conflict-free 1KB/wave kk-tile reads); q-halves merged in-wave via
// shfl_xor(32); dedup'd in-place class softmax; W register-prefetched
// (depth 1 in A, depth 2 in S) from bf16 L2-resident Wmb.
// All departures counter-refuted: 960-thr (RA pins 64 VGPR, 60 MB spill),
// dual-stream ILP (RA pins 84, 7 MB spill), W-via-LDS (barrier drains,
// 2x bank conflicts), f32 W (L2 thrash, FETCH 13->337 MB), kk-split pair
// (rendezvous cost +59 us), packed f32 (latency-bound: VALUBusy 64->56
// but time +1.5 us). Occupancy structurally pinned: grid = 256 blocks on
// 256 CUs, 1 batch/block; cross-class softmax coupling forbids splitting.
// ---------------------------------------------------------------------------
__global__ __launch_bounds__(640, 1) void em_kernel(
    const unsigned short* __restrict__ Cp,    // [512][6400] bf16 pose
    const float* __restrict__ Ca,             // [32][6400] fp32 activations
    const unsigned short* __restrict__ Wmb,   // [25][10][32][16] bf16
    const float* __restrict__ beta_u, const float* __restrict__ beta_a,
    float* __restrict__ out)                  // (256,10)
{
    __shared__ __align__(16) unsigned short psh[25][2][32][8]; // 25.6 KB bf16 pose
    __shared__ float aush[800];                                // 3.2 KB
    __shared__ float lnq[NCLS][800];                           // 32 KB ln_p, reused as rw
    __shared__ float mu_sh[NCLS][16];
    __shared__ float i2s_sh[NCLS][16];
    __shared__ float costp[2][NCLS];
    __shared__ float slgp[2][NCLS];
    __shared__ float Kc_sh[NCLS];
    __shared__ float aout_sh[NCLS];

    const int b = blockIdx.x, t = threadIdx.x;
    const int c = t >> 6;                     // wave = class
    const int rh = (t >> 5) & 1;              // half-wave = pose-dim half
    const int a = t & 31;                     // capsule lane

    // stage pose bf16: Cp[c2][b*25+px] -> psh[px][(c2&15)>>3][c2>>4][c2&7]
    const unsigned short* pb = Cp + (size_t)b * 25;
    for (int f = t; f < 12800; f += 640) {
        const int c2 = f / 25, px = f - c2 * 25;
        const int e = c2 & 15;
        psh[px][e >> 3][c2 >> 4][e & 7] = pb[(size_t)c2 * NTOT + px];
    }
    const float* ab = Ca + (size_t)b * 25;
    for (int f = t; f < 800; f += 640) {
        const int ci = f / 25, px = f - ci * 25;
        aush[px * 32 + ci] = ab[(size_t)ci * NTOT + px];
    }
    __syncthreads();

    const float bu = beta_u[c], ba = beta_a[c];
    float muL[8], i2sL[8], KcL = 0.f;
    const unsigned short* wbase = Wmb + ((size_t)(c * 32 + a)) * 16;  // + kk*5120

    // unpack 16 bf16 W (w0_,w1_) + 8 bf16 pose (p_), 32 FMA vote
    #define VOTE(w0_, w1_, p_, vv)                                           \
        {                                                                    \
            float pm[8], wv[16];                                             \
            const unsigned int pu[4] = {(unsigned)p_.x, (unsigned)p_.y,      \
                                        (unsigned)p_.z, (unsigned)p_.w};     \
            _Pragma("unroll")                                                \
            for (int i = 0; i < 4; ++i) {                                    \
                pm[2*i]   = __uint_as_float(pu[i] << 16);                    \
                pm[2*i+1] = __uint_as_float(pu[i] & 0xFFFF0000u);            \
            }                                                                \
            const unsigned int uu[8] = {(unsigned)w0_.x,(unsigned)w0_.y,     \
                (unsigned)w0_.z,(unsigned)w0_.w,(unsigned)w1_.x,             \
                (unsigned)w1_.y,(unsigned)w1_.z,(unsigned)w1_.w};            \
            _Pragma("unroll")                                                \
            for (int i = 0; i < 8; ++i) {                                    \
                wv[2*i]   = __uint_as_float(uu[i] << 16);                    \
                wv[2*i+1] = __uint_as_float(uu[i] & 0xFFFF0000u);            \
            }                                                                \
            _Pragma("unroll")                                                \
            for (int jr = 0; jr < 2; ++jr) {                                 \
                _Pragma("unroll")                                            \
                for (int s = 0; s < 4; ++s) {                                \
                    float av = 0.f;                                          \
                    _Pragma("unroll")                                        \
                    for (int tt = 0; tt < 4; ++tt)                           \
                        av = fmaf(pm[jr*4+tt], wv[tt*4+s], av);              \
                    vv[jr*4+s] = av;                                         \
                }                                                            \
            }                                                                \
        }

    float p95 = 1.f;
    for (int it = 0; it < 3; ++it) {
        p95 *= 0.95f;
        const float lam = 0.01f * (1.f - p95);

        if (it > 0) {
            // ---- phase A: ln_p, W depth-1 + pose depth-1 prefetch;
            //      halves merged in-wave via shfl_xor(32) ----
            int4 wr0 = *reinterpret_cast<const int4*>(wbase);
            int4 wr1 = *reinterpret_cast<const int4*>(wbase + 8);
            int4 pr  = *reinterpret_cast<const int4*>(&psh[0][rh][a][0]);
            for (int kk = 0; kk < 25; ++kk) {
                const int4 w0 = wr0, w1 = wr1, p = pr;
                if (kk < 24) {
                    const unsigned short* wn = wbase + (size_t)(kk + 1) * 5120;
                    wr0 = *reinterpret_cast<const int4*>(wn);
                    wr1 = *reinterpret_cast<const int4*>(wn + 8);
                    pr  = *reinterpret_cast<const int4*>(&psh[kk + 1][rh][a][0]);
                }
                float vv[8];
                VOTE(w0, w1, p, vv);
                float q = (rh == 0) ? KcL : 0.f;
                #pragma unroll
                for (int j = 0; j < 8; ++j) {
                    const float d = vv[j] - muL[j];
                    q -= d * d * i2sL[j];
                }
                q += __shfl_xor(q, 32);
                if (rh == 0) lnq[c][kk * 32 + a] = q;
            }
            __syncthreads();
            // ---- phase R (dedup, in-place): one thread per m does the
            //      class softmax once; rw overwrites lnq ----
            for (int m = t; m < 800; m += 640) {
                float qv[NCLS];
                #pragma unroll
                for (int cc = 0; cc < NCLS; ++cc) qv[cc] = lnq[cc][m];
                float mx = qv[0];
                #pragma unroll
                for (int cc = 1; cc < NCLS; ++cc) mx = fmaxf(mx, qv[cc]);
                float ev[NCLS];
                float den = 0.f;
                #pragma unroll
                for (int cc = 0; cc < NCLS; ++cc) {
                    ev[cc] = fexp(qv[cc] - mx);
                    den += ev[cc];
                }
                const float s = aush[m] * __builtin_amdgcn_rcpf(den);
                #pragma unroll
                for (int cc = 0; cc < NCLS; ++cc)
                    lnq[cc][m] = ev[cc] * s;
            }
            __syncthreads();
        }

        // ---- phase S: weighted stats, W depth-2 + pose depth-1 prefetch ----
        float S0 = 0.f, S1[8], S2[8];
        #pragma unroll
        for (int j = 0; j < 8; ++j) { S1[j] = 0.f; S2[j] = 0.f; }

        int4 wA0 = *reinterpret_cast<const int4*>(wbase);
        int4 wA1 = *reinterpret_cast<const int4*>(wbase + 8);
        int4 wB0 = *reinterpret_cast<const int4*>(wbase + 5120);
        int4 wB1 = *reinterpret_cast<const int4*>(wbase + 5120 + 8);
        int4 pr  = *reinterpret_cast<const int4*>(&psh[0][rh][a][0]);
        for (int kk = 0; kk < 25; ++kk) {
            const int4 w0 = wA0, w1 = wA1, p = pr;
            wA0 = wB0; wA1 = wB1;
            if (kk < 23) {
                const unsigned short* wn = wbase + (size_t)(kk + 2) * 5120;
                wB0 = *reinterpret_cast<const int4*>(wn);
                wB1 = *reinterpret_cast<const int4*>(wn + 8);
            }
            if (kk < 24)
                pr = *reinterpret_cast<const int4*>(&psh[kk + 1][rh][a][0]);
            float vv[8];
            VOTE(w0, w1, p, vv);
            const int m = kk * 32 + a;
            const float rw = (it == 0) ? aush[m] : lnq[c][m];
            S0 += rw;
            #pragma unroll
            for (int j = 0; j < 8; ++j) {
                const float rv = rw * vv[j];
                S1[j] += rv;
                S2[j] = fmaf(rv, vv[j], S2[j]);
            }
        }

        // butterfly over the 32 a-lanes (within half-wave)
        #pragma unroll
        for (int off = 16; off >= 1; off >>= 1) {
            S0 += __shfl_xor(S0, off);
            #pragma unroll
            for (int j = 0; j < 8; ++j) {
                S1[j] += __shfl_xor(S1[j], off);
                S2[j] += __shfl_xor(S2[j], off);
            }
        }

        // per-half epilogue (both rh halves hold the SAME full S0)
        if (a == 0) {
            const float s0e = S0 + 1e-12f;
            const float inv = 1.f / s0e;
            float cost_ = 0.f, slg_ = 0.f;
            #pragma unroll
            for (int j = 0; j < 8; ++j) {
                const float mu_ = S1[j] * inv;
                const float sg = (S2[j] - 2.f * mu_ * S1[j] + mu_ * mu_ * S0) * inv
                                 + 1e-12f;
                cost_ += bu + 0.5f * flog(sg);
                slg_ += flog(sg * LN2PI_F);
                mu_sh[c][rh * 8 + j] = mu_;
                i2s_sh[c][rh * 8 + j] = 0.5f / sg;
            }
            costp[rh][c] = cost_;
            slgp[rh][c] = slg_;
        }
        __syncthreads();
        if (a == 0 && rh == 0) {
            const float costsum = (costp[0][c] + costp[1][c]) * S0;
            const float aout = 1.f / (1.f + fexp(-(lam * (ba - costsum))));
            aout_sh[c] = aout;
            Kc_sh[c] = flog(aout) - 0.5f * (slgp[0][c] + slgp[1][c]);
        }
        __syncthreads();
        if (it < 2) {
            #pragma unroll
            for (int j = 0; j < 8; ++j) {
                muL[j] = mu_sh[c][rh * 8 + j];
                i2sL[j] = i2s_sh[c][rh * 8 + j];
            }
            KcL = Kc_sh[c];
        }
    }

    if (t < NCLS) {
        float s = 0.f;
        #pragma unroll
        for (int cc = 0; cc < NCLS; ++cc) s += aout_sh[cc];
        out[b * NCLS + t] = flog(aout_sh[t] / s);
    }
    #undef VOTE
}

// ---------------------------------------------------------------------------
extern "C" void kernel_launch(void* const* d_in, const int* in_sizes, int n_in,
                              void* d_out, int out_size, void* d_ws, size_t ws_size,
                              hipStream_t stream) {
    const float* x      = (const float*)d_in[0];
    const float* w_a    = (const float*)d_in[1];
    const float* w_pose = (const float*)d_in[2];
    const float* bn_a_g = (const float*)d_in[3];
    const float* bn_a_b = (const float*)d_in[4];
    const float* bn_a_m = (const float*)d_in[5];
    const float* bn_a_v = (const float*)d_in[6];
    const float* bn_p_g = (const float*)d_in[7];
    const float* bn_p_b = (const float*)d_in[8];
    const float* bn_p_m = (const float*)d_in[9];
    const float* bn_p_v = (const float*)d_in[10];
    const float* Wm     = (const float*)d_in[11];
    const float* beta_u = (const float*)d_in[12];
    const float* beta_a = (const float*)d_in[13];
    float* out = (float*)d_out;

    char* p = (char*)d_ws;
    unsigned short* At  = (unsigned short*)p;  p += (size_t)MPAD * KDIM * 2;
    unsigned short* Bt  = (unsigned short*)p;  p += (size_t)NTOT * KDIM * 2;
    unsigned short* Wmb = (unsigned short*)p;  p += (size_t)800 * NCLS * 16 * 2;
    unsigned short* Cp  = (unsigned short*)p;  p += (size_t)512 * NTOT * 2;
    float* Ca = (float*)p;                     p += (size_t)32 * NTOT * 4;
    float* sc = (float*)p;                     p += MPAD * 4;
    float* bi = (float*)p;                     p += MPAD * 4;

    pack_a_kernel<<<NABLK + 63, 256, 0, stream>>>(w_pose, w_a,
                                                  bn_p_g, bn_p_b, bn_p_m, bn_p_v,
                                                  bn_a_g, bn_a_b, bn_a_m, bn_a_v,
                                                  Wm, At, Wmb, sc, bi);
    pack_b_kernel<<<256, 1024, 0, stream>>>(x, Bt);
    gemm_kernel<<<250, 1024, 0, stream>>>(At, Bt, sc, bi, Cp, Ca);
    em_kernel<<<256, 640, 0, stream>>>(Cp, Ca, Wmb, beta_u, beta_a, out);
}